// Round 2
// baseline (138.517 us; speedup 1.0000x reference)
//
#include <hip/hip_runtime.h>

// SetConv RBF: B=4, NQ=4096, NC=4096, DC=2, DY=8, fp32.
// out[b,q,0:8] = sum_c w(q,c)*y[c] / (den+1e-8); out[b,q,8] = den = sum_c w(q,c)
//
// MEASURED LAWS (R1-R10 prior session, R11 this session):
//  - dur_us includes ~41us harness d_ws poison fill (268MB, fixed) + ~10us fixed.
//  - MFMA accum path plateaus ~20us accum + 2.5us reduce (73.6 total).
//  - R11 binning (12x12 grid, cell 0.75): absmax 0.0019 => window truncation at
//    1 cell ring is numerically safe (tail < 2.5e-9 vs 1e-8 floor). BUT:
//    sc_main 42us @ VALUBusy 17%, Occ 23% => latency-bound: 128-iter serial
//    uniform-load chains, ~3 waves/SIMD, half the waves exited early.
//    sc_bin ~35us: 8 blocks, 12 scalar scattered stores/point.
// R12: fixed 48 slices/chunk (~30 iter/wave, 12K waves, 8/SIMD), readfirstlane
// scalarization of all window math, block=4 slices LDS-reduced -> 12 partials.
// Binning: sc_hist (8 blk) + sc_scatter (64 blk, float4 stores, atomic cursors).
// Predicted: main 5-8us, hist+scatter ~6us, fin ~2us, total ~66-70us.

#define BB 4
#define NQ 4096
#define NC 4096
#define DY 8
#define NBQ (BB * NQ)           // 16384 queries total

#if __has_builtin(__builtin_amdgcn_exp2f)
#define EXP2F(x) __builtin_amdgcn_exp2f(x)
#else
#define EXP2F(x) exp2f(x)
#endif

// ================= binned path (R12) =================
#define NGX 12
#define NGY 12
#define INVW (1.0f / 0.75f)
#define XMIN (-4.5f)
#define CSTRIDE 16                     // cell id = row*16 + col (cols 12..15 empty)
#define NCID (NGY * CSTRIDE)           // 192 cell ids
#define NCELL1 (NCID + 1)              // 193
#define SL 48                          // slices per chunk (fixed, no early exit)
#define SGRP 12                        // slice groups of 4 (one block each)
#define NCHUNK 256                     // 16384 sorted queries / 64

// ws layout in 4-byte units
#define OFF_CSTART 0                   // int[4][193]          (ctx cell starts)
#define OFF_CUR    1024                // int[8][192]          (scatter cursors)
#define OFF_QINFO  4096                // int[16384]           (qid | cell<<16)
#define OFF_QXY    20480               // float[2*16384]       (sorted scaled q)
#define OFF_CREC   53248               // float[16384*12]      (sorted ctx recs)
#define OFF_PART   249856              // float[SGRP*9*16384]  (partials)
#define WS_NEED_FLOATS (OFF_PART + SGRP * 9 * NBQ)   // 2,019,328 ~ 8.1 MB

// --- K1: per-(batch,kind) block: LDS hist + scan -> starts/cursors ---
__global__ __launch_bounds__(256) void sc_hist(
    const float* __restrict__ xq, const float* __restrict__ xc,
    float* __restrict__ wsf)
{
    __shared__ int s_hist[NCID];
    __shared__ int s_scan[256];
    const int tid  = threadIdx.x;
    const int b    = blockIdx.x >> 1;
    const int kind = blockIdx.x & 1;   // 0 = context, 1 = query
    int* wsi = (int*)wsf;

    for (int i = tid; i < NCID; i += 256) s_hist[i] = 0;
    __syncthreads();

    const float2* src = ((const float2*)(kind ? xq : xc)) + (size_t)b * 4096;
#pragma unroll
    for (int i = 0; i < 16; ++i) {
        const float2 v = src[tid + 256 * i];
        const int cx = min(max((int)floorf((v.x - XMIN) * INVW), 0), NGX - 1);
        const int cy = min(max((int)floorf((v.y - XMIN) * INVW), 0), NGY - 1);
        atomicAdd(&s_hist[cy * CSTRIDE + cx], 1);
    }
    __syncthreads();

    s_scan[tid] = (tid < NCID) ? s_hist[tid] : 0;
    __syncthreads();
#pragma unroll
    for (int off = 1; off < 256; off <<= 1) {
        const int t = (tid >= off) ? s_scan[tid - off] : 0;
        __syncthreads();
        s_scan[tid] += t;
        __syncthreads();
    }
    const int start = (tid == 0) ? 0 : s_scan[tid - 1];   // exclusive
    if (tid < NCID) wsi[OFF_CUR + (b * 2 + kind) * NCID + tid] = start;
    if (kind == 0) {
        if (tid < NCID) wsi[OFF_CSTART + b * NCELL1 + tid] = start;
        if (tid == 0)   wsi[OFF_CSTART + b * NCELL1 + NCID] = 4096;
    }
}

// --- K2: scatter points into cell-sorted arrays (64 blocks, atomic cursors) ---
__global__ __launch_bounds__(256) void sc_scatter(
    const float* __restrict__ xq, const float* __restrict__ xc,
    const float* __restrict__ yc, const float* __restrict__ lls,
    float* __restrict__ wsf)
{
    const int tid  = threadIdx.x;
    const int g    = blockIdx.x >> 3;        // 0..7 = (b<<1)|kind
    const int b    = g >> 1;
    const int kind = g & 1;
    int* wsi = (int*)wsf;

    const float L   = lls[0];
    // scaled coords: t = -(dx^2+dy^2) with coords *= sig, sig^2 = log2(e)/(2 ls^2)
    const float sig = sqrtf(0.72134752044448f * EXP2F(-2.8853900817779268f * L));

    const float2* src = ((const float2*)(kind ? xq : xc)) + (size_t)b * 4096;
#pragma unroll
    for (int k = 0; k < 2; ++k) {
        const int i = (blockIdx.x & 7) * 512 + k * 256 + tid;
        const float2 v = src[i];
        const int cx = min(max((int)floorf((v.x - XMIN) * INVW), 0), NGX - 1);
        const int cy = min(max((int)floorf((v.y - XMIN) * INVW), 0), NGY - 1);
        const int cell = cy * CSTRIDE + cx;
        const int pos  = atomicAdd(&wsi[OFF_CUR + g * NCID + cell], 1);
        if (kind == 0) {
            const float4* yp = (const float4*)(yc + ((size_t)b * 4096 + i) * DY);
            const float4 A  = yp[0];
            const float4 Bv = yp[1];
            float4* d = (float4*)(wsf + OFF_CREC + ((size_t)b * 4096 + pos) * 12);
            d[0] = make_float4(sig * v.x, sig * v.y, A.x, A.y);
            d[1] = make_float4(A.z, A.w, Bv.x, Bv.y);
            d[2] = make_float4(Bv.z, Bv.w, 0.f, 0.f);
        } else {
            const int g2 = b * 4096 + pos;
            ((float2*)(wsf + OFF_QXY))[g2] = make_float2(sig * v.x, sig * v.y);
            wsi[OFF_QINFO + g2] = i | (cell << 16);
        }
    }
}

// --- K3: wave = (64-query chunk, slice of its ctx window). 48 slices/chunk,
//     4 slices per block (same chunk), LDS reduce -> 12 partial groups. ---
__global__ __launch_bounds__(256, 8) void sc_main(
    const float* __restrict__ crec, const int* __restrict__ cstart,
    const int* __restrict__ qinfo, const float* __restrict__ qxy,
    float* __restrict__ part)
{
    __shared__ float red[4][64][9];
    const int lane  = threadIdx.x & 63;
    const int wv    = threadIdx.x >> 6;
    const int sg    = blockIdx.x;            // 0..11
    const int chunk = blockIdx.y;            // 0..255
    const int s     = sg * 4 + wv;           // slice 0..47
    const int b     = chunk >> 6;
    const int p     = chunk * 64 + lane;     // global sorted query position

    const float qx = qxy[2 * p], qy = qxy[2 * p + 1];

    // chunk window from first/last sorted cell (forced scalar)
    const int q0  = __builtin_amdgcn_readfirstlane(qinfo[chunk * 64]);
    const int q1  = __builtin_amdgcn_readfirstlane(qinfo[chunk * 64 + 63]);
    const int cf  = q0 >> 16, cl_ = q1 >> 16;
    const int rf  = cf >> 4,  rl  = cl_ >> 4;
    const int r0  = max(rf - 1, 0), r1 = min(rl + 1, NGY - 1);
    int c0, c1;
    if (rf == rl) { c0 = max((cf & 15) - 1, 0); c1 = min((cl_ & 15) + 1, NGX - 1); }
    else          { c0 = 0; c1 = NGX - 1; }    // row-spanning: full width

    const int* cs = cstart + b * NCELL1;
    int M = 0;
    for (int r = r0; r <= r1; ++r)
        M += __builtin_amdgcn_readfirstlane(cs[r * CSTRIDE + c1 + 1]) -
             __builtin_amdgcn_readfirstlane(cs[r * CSTRIDE + c0]);

    const int Teff = (M + SL - 1) / SL;      // ~30 avg, ~94 worst
    float a0=0.f,a1=0.f,a2=0.f,a3=0.f,a4=0.f,a5=0.f,a6=0.f,a7=0.f,a8=0.f;
    int o   = s * Teff;
    int rem = min(Teff, M - o);
    for (int r = r0; r <= r1 && rem > 0; ++r) {
        const int base = __builtin_amdgcn_readfirstlane(cs[r * CSTRIDE + c0]);
        const int len  = __builtin_amdgcn_readfirstlane(cs[r * CSTRIDE + c1 + 1]) - base;
        if (o >= len) { o -= len; continue; }
        const int cnt = min(len - o, rem);
        const float4* rp = (const float4*)(crec + ((size_t)b * 4096 + base + o) * 12);
        o = 0; rem -= cnt;
        for (int i = 0; i < cnt; ++i, rp += 3) {
            const float4 A  = rp[0];                 // sx, sy, y0, y1
            const float4 Bv = rp[1];                 // y2..y5
            const float4 Cv = rp[2];                 // y6, y7, pad, pad
            const float dx = A.x - qx, dy = A.y - qy;
            const float w  = EXP2F(-fmaf(dy, dy, dx * dx));
            a8 += w;
            a0 = fmaf(w, A.z,  a0); a1 = fmaf(w, A.w,  a1);
            a2 = fmaf(w, Bv.x, a2); a3 = fmaf(w, Bv.y, a3);
            a4 = fmaf(w, Bv.z, a4); a5 = fmaf(w, Bv.w, a5);
            a6 = fmaf(w, Cv.x, a6); a7 = fmaf(w, Cv.y, a7);
        }
    }

    red[wv][lane][0]=a0; red[wv][lane][1]=a1; red[wv][lane][2]=a2;
    red[wv][lane][3]=a3; red[wv][lane][4]=a4; red[wv][lane][5]=a5;
    red[wv][lane][6]=a6; red[wv][lane][7]=a7; red[wv][lane][8]=a8;
    __syncthreads();
    if (wv == 0) {
#pragma unroll
        for (int j = 0; j < 9; ++j) {
            const float v = red[0][lane][j] + red[1][lane][j] +
                            red[2][lane][j] + red[3][lane][j];
            part[((size_t)sg * 9 + j) * NBQ + p] = v;   // coalesced
        }
    }
}

// --- K4: sum 12 groups, normalize, scatter to original query order ---
__global__ __launch_bounds__(256) void sc_fin(
    const float* __restrict__ part, const int* __restrict__ qinfo,
    float* __restrict__ out)
{
    const int p = blockIdx.x * 256 + threadIdx.x;   // sorted position
    float sum[9];
#pragma unroll
    for (int j = 0; j < 9; ++j) sum[j] = 0.f;
#pragma unroll
    for (int sg = 0; sg < SGRP; ++sg) {
        const float* pp = part + ((size_t)sg * 9) * NBQ + p;
#pragma unroll
        for (int j = 0; j < 9; ++j) sum[j] += pp[j * NBQ];
    }
    const int qid = qinfo[p] & 0xFFFF;
    const int b   = p >> 12;
    const float inv = 1.f / (sum[8] + 1e-8f);
    float* o = out + ((size_t)b * 4096 + qid) * 9;
#pragma unroll
    for (int j = 0; j < 8; ++j) o[j] = sum[j] * inv;
    o[8] = sum[8];
}

// ================= previous MFMA path (kept for one-line revert) =================
typedef short bf16x8 __attribute__((ext_vector_type(8)));
typedef float f32x4  __attribute__((ext_vector_type(4)));
typedef float f32x2  __attribute__((ext_vector_type(2)));

__device__ __forceinline__ short f2bf(float v) {
    return (short)(__builtin_bit_cast(unsigned, v) >> 16);
}
__device__ __forceinline__ unsigned fbits(float v) {
    return __builtin_bit_cast(unsigned, v);
}
__device__ __forceinline__ unsigned bfpair(float w0, float w1) {
#if __has_builtin(__builtin_amdgcn_perm)
    return __builtin_amdgcn_perm(fbits(w1), fbits(w0), 0x07060302u);
#else
    return (fbits(w1) & 0xFFFF0000u) | (fbits(w0) >> 16);
#endif
}

#define GSPLIT 8
#define CCHUNK (NC / GSPLIT)
#define NPAIR (CCHUNK / 2)
#define KSTEPS (CCHUNK / 32)
#define QPB 128
#define QB (NBQ / QPB)
#define JS ((size_t)GSPLIT * NBQ)
#define WS_FLOATS ((size_t)(DY + 1) * GSPLIT * NBQ)

__global__ __launch_bounds__(256, 4) void setconv_accum_mfma(
    const float* __restrict__ xq, const float* __restrict__ xc,
    const float* __restrict__ yc, const float* __restrict__ lls,
    float* __restrict__ ws)
{
    __shared__ float4 sxp[NPAIR];
    __shared__ float2 shp[NPAIR];
    __shared__ unsigned short yfrag[CCHUNK / 8][16][8];

    const int bid  = blockIdx.x;
    const int gs   = bid & (GSPLIT - 1);
    const int qb   = bid >> 3;
    const int b    = qb >> 5;
    const int tid  = threadIdx.x;
    const int lane = tid & 63;
    const int wv   = tid >> 6;
    const int m    = lane & 15;
    const int quad = lane >> 4;

    const float L    = lls[0];
    const float negk = -0.72134752044448f * EXP2F(L * -2.8853900817779268f);

    {
        const float4* xcp = (const float4*)(((const float2*)xc) + (size_t)b * NC + gs * CCHUNK);
        const float4 v = xcp[tid];
        sxp[tid] = make_float4(v.x, v.z, v.y, v.w);
        shp[tid] = make_float2(negk * fmaf(v.x, v.x, v.y * v.y),
                               negk * fmaf(v.z, v.z, v.w * v.w));
    }
    {
        const float4* yp = (const float4*)(yc + ((size_t)b * NC + gs * CCHUNK) * DY);
#pragma unroll
        for (int i = 0; i < 2; ++i) {
            const int c = tid + 256 * i;
            const float4 A  = yp[2 * c + 0];
            const float4 Bv = yp[2 * c + 1];
            const int g = c >> 3, j = c & 7;
            unsigned short* dst = &yfrag[g][0][j];
            dst[0 * 8] = (unsigned short)f2bf(A.x);
            dst[1 * 8] = (unsigned short)f2bf(A.y);
            dst[2 * 8] = (unsigned short)f2bf(A.z);
            dst[3 * 8] = (unsigned short)f2bf(A.w);
            dst[4 * 8] = (unsigned short)f2bf(Bv.x);
            dst[5 * 8] = (unsigned short)f2bf(Bv.y);
            dst[6 * 8] = (unsigned short)f2bf(Bv.z);
            dst[7 * 8] = (unsigned short)f2bf(Bv.w);
        }
        unsigned* yf32 = (unsigned*)yfrag;
#pragma unroll
        for (int i = 0; i < 8; ++i) {
            const int v = tid + 256 * i;
            const int g = v >> 5, r = v & 31;
            yf32[g * 64 + 32 + r] = (r < 4) ? 0x3F803F80u : 0u;
        }
    }

    f32x2 A0[2], A1[2], A2[2];
#pragma unroll
    for (int t = 0; t < 2; ++t) {
        const int q = qb * QPB + (wv * 2 + t) * 16 + m;
        const float2 qv = ((const float2*)xq)[q];
        const float c0 = negk * fmaf(qv.x, qv.x, qv.y * qv.y);
        const float c1 = -2.f * negk * qv.x;
        const float c2 = -2.f * negk * qv.y;
        A0[t] = (f32x2){c0, c0};
        A1[t] = (f32x2){c1, c1};
        A2[t] = (f32x2){c2, c2};
    }

    f32x4 acc0 = {0.f, 0.f, 0.f, 0.f};
    f32x4 acc1 = {0.f, 0.f, 0.f, 0.f};

    __syncthreads();

#pragma unroll 2
    for (int s = 0; s < KSTEPS; ++s) {
        const bf16x8 bfrag = *(const bf16x8*)&yfrag[s * 4 + quad][m][0];
        unsigned au0[4], au1[4];
#pragma unroll
        for (int jp = 0; jp < 4; ++jp) {
            const int P = s * 16 + quad * 4 + jp;
            const float4 xp = sxp[P];
            const float2 hp = shp[P];
            const f32x2 cx2 = {xp.x, xp.y};
            const f32x2 cy2 = {xp.z, xp.w};
            const f32x2 hc2 = {hp.x, hp.y};
            f32x2 t0 = __builtin_elementwise_fma(cx2, A1[0], hc2 + A0[0]);
            t0 = __builtin_elementwise_fma(cy2, A2[0], t0);
            f32x2 t1 = __builtin_elementwise_fma(cx2, A1[1], hc2 + A0[1]);
            t1 = __builtin_elementwise_fma(cy2, A2[1], t1);
            au0[jp] = bfpair(EXP2F(t0.x), EXP2F(t0.y));
            au1[jp] = bfpair(EXP2F(t1.x), EXP2F(t1.y));
        }
        const bf16x8 af0 = __builtin_bit_cast(bf16x8, *(uint4*)au0);
        const bf16x8 af1 = __builtin_bit_cast(bf16x8, *(uint4*)au1);
        acc0 = __builtin_amdgcn_mfma_f32_16x16x32_bf16(af0, bfrag, acc0, 0, 0, 0);
        acc1 = __builtin_amdgcn_mfma_f32_16x16x32_bf16(af1, bfrag, acc1, 0, 0, 0);
    }

    if (m <= 8) {
        const size_t base = (size_t)m * JS + (size_t)gs * NBQ + (size_t)qb * QPB;
#pragma unroll
        for (int r = 0; r < 4; ++r) {
            ws[base + (wv * 2 + 0) * 16 + quad * 4 + r] = acc0[r];
            ws[base + (wv * 2 + 1) * 16 + quad * 4 + r] = acc1[r];
        }
    }
}

__global__ __launch_bounds__(256) void setconv_reduce(
    const float* __restrict__ ws, float* __restrict__ out)
{
    __shared__ float partl[4][64][DY + 1];
    const int tid  = threadIdx.x;
    const int qi   = tid & 63;
    const int sgp  = tid >> 6;
    const int base = blockIdx.x * 64;
    const int bq   = base + qi;

#pragma unroll
    for (int j = 0; j < DY + 1; ++j) {
        float s = 0.f;
#pragma unroll
        for (int k = 0; k < GSPLIT / 4; ++k) {
            const int split = sgp * (GSPLIT / 4) + k;
            s += ws[(size_t)j * JS + (size_t)split * NBQ + bq];
        }
        partl[sgp][qi][j] = s;
    }
    __syncthreads();

    for (int it = tid; it < 64 * (DY + 1); it += 256) {
        const int q2 = it / (DY + 1);
        const int j  = it - q2 * (DY + 1);
        const float den = partl[0][q2][DY] + partl[1][q2][DY] +
                          partl[2][q2][DY] + partl[3][q2][DY];
        float v;
        if (j == DY) {
            v = den;
        } else {
            const float s = partl[0][q2][j] + partl[1][q2][j] +
                            partl[2][q2][j] + partl[3][q2][j];
            v = s / (den + 1e-8f);
        }
        out[(size_t)base * (DY + 1) + it] = v;
    }
}

// ================= fallback path (round-1, known-good): atomics =================
#define FSPLIT 8
#define FCCH (NC / FSPLIT)

__global__ __launch_bounds__(256) void setconv_zero(float4* __restrict__ out) {
    out[blockIdx.x * 256 + threadIdx.x] = make_float4(0.f, 0.f, 0.f, 0.f);
}

__global__ __launch_bounds__(256) void setconv_accum_atomic(
    const float* __restrict__ xq, const float* __restrict__ xc,
    const float* __restrict__ yc, const float* __restrict__ lls,
    float* __restrict__ out)
{
    const int bid   = blockIdx.x;
    const int split = bid & (FSPLIT - 1);
    const int qblk  = (bid / FSPLIT) & (NQ / 256 - 1);
    const int b     = bid / (FSPLIT * (NQ / 256));
    const int q     = qblk * 256 + threadIdx.x;

    const float L    = lls[0];
    const float negk = -0.72134752044448f * EXP2F(L * -2.8853900817779268f);

    const float2 qv = ((const float2*)xq)[b * NQ + q];
    const float qx0 = qv.x, qy0 = qv.y;

    float acc[DY], den = 0.f;
#pragma unroll
    for (int j = 0; j < DY; ++j) acc[j] = 0.f;

    const float2* __restrict__ xcp = ((const float2*)xc) + (size_t)b * NC;
    const float4* __restrict__ ycp = ((const float4*)yc) + (size_t)b * NC * 2;

    const int c0 = split * FCCH;
#pragma unroll 4
    for (int c = c0; c < c0 + FCCH; ++c) {
        const float2 cv = xcp[c];
        const float4 y0 = ycp[2 * c + 0];
        const float4 y1 = ycp[2 * c + 1];
        const float dx = qx0 - cv.x;
        const float dy = qy0 - cv.y;
        const float d2 = fmaf(dy, dy, dx * dx);
        const float w  = EXP2F(d2 * negk);
        den += w;
        acc[0] = fmaf(w, y0.x, acc[0]);
        acc[1] = fmaf(w, y0.y, acc[1]);
        acc[2] = fmaf(w, y0.z, acc[2]);
        acc[3] = fmaf(w, y0.w, acc[3]);
        acc[4] = fmaf(w, y1.x, acc[4]);
        acc[5] = fmaf(w, y1.y, acc[5]);
        acc[6] = fmaf(w, y1.z, acc[6]);
        acc[7] = fmaf(w, y1.w, acc[7]);
    }

    float* o = out + (size_t)(b * NQ + q) * (DY + 1);
#pragma unroll
    for (int j = 0; j < DY; ++j) atomicAdd(o + j, acc[j]);
    atomicAdd(o + DY, den);
}

__global__ __launch_bounds__(256) void setconv_norm(float* __restrict__ out) {
    const int q = blockIdx.x * 256 + threadIdx.x;
    float* o = out + (size_t)q * (DY + 1);
    const float inv = 1.0f / (o[DY] + 1e-8f);
#pragma unroll
    for (int j = 0; j < DY; ++j) o[j] *= inv;
}

extern "C" void kernel_launch(void* const* d_in, const int* in_sizes, int n_in,
                              void* d_out, int out_size, void* d_ws, size_t ws_size,
                              hipStream_t stream) {
    const float* xq  = (const float*)d_in[0];  // (4,4096,2)
    const float* xc  = (const float*)d_in[1];  // (4,4096,2)
    const float* yc  = (const float*)d_in[2];  // (4,4096,8)
    const float* lls = (const float*)d_in[3];  // scalar
    float* out = (float*)d_out;                // (4,4096,9)

    if (ws_size >= (size_t)WS_NEED_FLOATS * sizeof(float)) {
        float* wsf = (float*)d_ws;
        int*   wsi = (int*)d_ws;
        sc_hist<<<BB * 2, 256, 0, stream>>>(xq, xc, wsf);
        sc_scatter<<<64, 256, 0, stream>>>(xq, xc, yc, lls, wsf);
        dim3 mg(SGRP, NCHUNK);
        sc_main<<<mg, 256, 0, stream>>>(
            wsf + OFF_CREC, wsi + OFF_CSTART, wsi + OFF_QINFO,
            wsf + OFF_QXY, wsf + OFF_PART);
        sc_fin<<<NBQ / 256, 256, 0, stream>>>(
            wsf + OFF_PART, wsi + OFF_QINFO, out);
    } else if (ws_size >= WS_FLOATS * sizeof(float)) {
        float* ws = (float*)d_ws;
        setconv_accum_mfma<<<QB * GSPLIT, 256, 0, stream>>>(xq, xc, yc, lls, ws);
        setconv_reduce<<<NBQ / 64, 256, 0, stream>>>(ws, out);
    } else {
        setconv_zero<<<(NBQ * (DY + 1)) / 1024, 256, 0, stream>>>((float4*)out);
        setconv_accum_atomic<<<BB * (NQ / 256) * FSPLIT, 256, 0, stream>>>(xq, xc, yc, lls, out);
        setconv_norm<<<NBQ / 256, 256, 0, stream>>>(out);
    }
}

// Round 3
// 118.490 us; speedup vs baseline: 1.1690x; 1.1690x over previous
//
#include <hip/hip_runtime.h>

// SetConv RBF: B=4, NQ=4096, NC=4096, DC=2, DY=8, fp32.
// out[b,q,0:8] = sum_c w(q,c)*y[c] / (den+1e-8); out[b,q,8] = den = sum_c w(q,c)
//
// MEASURED LAWS (R1-R10 prior session, R11-R12 this session):
//  - dur_us includes ~41us harness d_ws poison fill (268MB, fixed) + ~10us fixed.
//  - MFMA dense path: 20us accum + 2.5us reduce = 73.6 total (67M pairs).
//  - Binning (12x12 grid, cell 0.75): absmax 0.0019 => 1-ring window truncation
//    numerically safe (tail < 2.5e-9 vs 1e-8 density floor). ~21M pairs.
//  - R11/R12 FAILURE LAW: any accumulator whose inner loop issues GLOBAL loads
//    per trip is latency-bound regardless of occupancy (R12: 59.9us @ VALU 16%,
//    occ 48% -- VALU cycles == useful work, 84% un-hidden L2 latency).
//    Corollary: hot loop must read ctx from LDS (the 20us MFMA kernel does).
//  - R12 secondary: hist(8blk LDS atomics)+scatter+fin+gaps ~= 25us.
// R13: sc_chunk = 32 sorted queries/block, 512 thr (tid=s*32+q), window walked
// in 256-rec tiles double-buffered in LDS; per-wave ds_read = 2 distinct addrs
// (free). hist -> 64 blocks private hists (no atomics, no zero); 1-block scan.
// Predicted: chunk 5-8us VALU 40-60%, binning ~5us, total ~64-70us.

#define BB 4
#define NQ 4096
#define NC 4096
#define DY 8
#define NBQ (BB * NQ)           // 16384 queries total

#if __has_builtin(__builtin_amdgcn_exp2f)
#define EXP2F(x) __builtin_amdgcn_exp2f(x)
#else
#define EXP2F(x) exp2f(x)
#endif

// ================= binned path (R13) =================
#define NGX 12
#define NGY 12
#define INVW (1.0f / 0.75f)
#define XMIN (-4.5f)
#define CSTRIDE 16                     // cell id = row*16 + col (cols 12..15 empty)
#define NCID (NGY * CSTRIDE)           // 192 cell ids
#define NCELL1 (NCID + 1)              // 193

#define QCH 32                         // queries per chunk (= per block)
#define NCHK (NBQ / QCH)               // 512 chunks
#define TS 256                         // ctx records per LDS tile
#define SGN 16                         // ctx sub-groups per query
#define RECF 12                        // floats per ctx record
#define GRPF (16 * RECF + 4)           // 196 floats per s-group region (pad 4)
#define BUFF (SGN * GRPF)              // 3136 floats per tile buffer

// ws layout in 4-byte units
#define OFF_CSTART 0                   // int[4][193]      ctx cell starts
#define OFF_H2     1024                // int[64][192]     per-block private hists
#define OFF_CUR    16384               // int[8][192]      scatter cursors
#define OFF_QINFO  20480               // int[16384]       (qid | cell<<16) sorted
#define OFF_QXY    40960               // float[2*16384]   sorted scaled coords
#define OFF_CREC   81920               // float[16384*12]  sorted ctx records
#define WS_NEED_FLOATS (OFF_CREC + NBQ * RECF)   // 278,528 ~ 1.1 MB

// --- K1: 64 blocks, each: LDS hist of 512 points -> private global hist row ---
__global__ __launch_bounds__(256) void sc_hist(
    const float* __restrict__ xq, const float* __restrict__ xc,
    float* __restrict__ wsf)
{
    __shared__ int h[NCID];
    const int tid  = threadIdx.x;
    const int g    = blockIdx.x >> 3;      // 0..7 = (b<<1)|kind
    const int b    = g >> 1;
    const int kind = g & 1;
    int* wsi = (int*)wsf;

    for (int i = tid; i < NCID; i += 256) h[i] = 0;
    __syncthreads();

    const float2* src = ((const float2*)(kind ? xq : xc)) + (size_t)b * 4096;
#pragma unroll
    for (int k = 0; k < 2; ++k) {
        const int i = (blockIdx.x & 7) * 512 + k * 256 + tid;
        const float2 v = src[i];
        const int cx = min(max((int)floorf((v.x - XMIN) * INVW), 0), NGX - 1);
        const int cy = min(max((int)floorf((v.y - XMIN) * INVW), 0), NGY - 1);
        atomicAdd(&h[cy * CSTRIDE + cx], 1);
    }
    __syncthreads();
    if (tid < NCID) wsi[OFF_H2 + blockIdx.x * NCID + tid] = h[tid];
}

// --- K2: 1 block: sum 8 private hists per group, scan, write starts+cursors ---
__global__ __launch_bounds__(256) void sc_scan(float* __restrict__ wsf)
{
    __shared__ int s_scan[256];
    const int tid = threadIdx.x;
    int* wsi = (int*)wsf;

    for (int g = 0; g < 8; ++g) {
        int v = 0;
        if (tid < NCID)
#pragma unroll
            for (int k = 0; k < 8; ++k)
                v += wsi[OFF_H2 + (g * 8 + k) * NCID + tid];
        s_scan[tid] = (tid < NCID) ? v : 0;
        __syncthreads();
#pragma unroll
        for (int off = 1; off < 256; off <<= 1) {
            const int t = (tid >= off) ? s_scan[tid - off] : 0;
            __syncthreads();
            s_scan[tid] += t;
            __syncthreads();
        }
        const int start = (tid == 0) ? 0 : s_scan[tid - 1];   // exclusive
        if (tid < NCID) wsi[OFF_CUR + g * NCID + tid] = start;
        if ((g & 1) == 0) {
            const int b = g >> 1;
            if (tid < NCID) wsi[OFF_CSTART + b * NCELL1 + tid] = start;
            if (tid == 0)   wsi[OFF_CSTART + b * NCELL1 + NCID] = 4096;
        }
        __syncthreads();
    }
}

// --- K3: scatter points into cell-sorted arrays (64 blocks, atomic cursors) ---
__global__ __launch_bounds__(256) void sc_scatter(
    const float* __restrict__ xq, const float* __restrict__ xc,
    const float* __restrict__ yc, const float* __restrict__ lls,
    float* __restrict__ wsf)
{
    const int tid  = threadIdx.x;
    const int g    = blockIdx.x >> 3;        // 0..7 = (b<<1)|kind
    const int b    = g >> 1;
    const int kind = g & 1;
    int* wsi = (int*)wsf;

    const float L   = lls[0];
    // scaled coords: w = exp2(-(dx^2+dy^2)); sig^2 = log2(e)/(2 ls^2)
    const float sig = sqrtf(0.72134752044448f * EXP2F(-2.8853900817779268f * L));

    const float2* src = ((const float2*)(kind ? xq : xc)) + (size_t)b * 4096;
#pragma unroll
    for (int k = 0; k < 2; ++k) {
        const int i = (blockIdx.x & 7) * 512 + k * 256 + tid;
        const float2 v = src[i];
        const int cx = min(max((int)floorf((v.x - XMIN) * INVW), 0), NGX - 1);
        const int cy = min(max((int)floorf((v.y - XMIN) * INVW), 0), NGY - 1);
        const int cell = cy * CSTRIDE + cx;
        const int pos  = atomicAdd(&wsi[OFF_CUR + g * NCID + cell], 1);
        if (kind == 0) {
            const float4* yp = (const float4*)(yc + ((size_t)b * 4096 + i) * DY);
            const float4 A  = yp[0];
            const float4 Bv = yp[1];
            float4* d = (float4*)(wsf + OFF_CREC + ((size_t)b * 4096 + pos) * RECF);
            d[0] = make_float4(sig * v.x, sig * v.y, A.x, A.y);
            d[1] = make_float4(A.z, A.w, Bv.x, Bv.y);
            d[2] = make_float4(Bv.z, Bv.w, 0.f, 0.f);
        } else {
            const int g2 = b * 4096 + pos;
            ((float2*)(wsf + OFF_QXY))[g2] = make_float2(sig * v.x, sig * v.y);
            wsi[OFF_QINFO + g2] = i | (cell << 16);
        }
    }
}

// --- K4: block = one 32-query chunk. Window tiled through LDS (double-buffered);
//     hot loop reads ctx ONLY from LDS (R12 failure law). Writes final output. ---
__global__ __launch_bounds__(512, 4) void sc_chunk(
    const float* __restrict__ crec, const int* __restrict__ cstart,
    const int* __restrict__ qinfo, const float* __restrict__ qxy,
    float* __restrict__ out)
{
    __shared__ float smem[2 * BUFF];       // 25 KB tiles; reused as reduce buffer
    __shared__ int   dbase[12];            // window row directory
    __shared__ int   dcum[13];
    __shared__ int   sMsh;
    __shared__ float sden[QCH];

    const int tid   = threadIdx.x;
    const int chunk = blockIdx.x;          // 0..511
    const int b     = chunk >> 7;          // 128 chunks per batch
    const int s     = tid >> 5;            // 0..15 ctx sub-group
    const int q     = tid & 31;            // query within chunk
    const int p     = chunk * QCH + q;     // global sorted query position

    // ---- preamble: wave 0 builds the window row-directory (scalar-ish) ----
    if (tid < 64) {
        const int lane = tid;
        int cellv = 0;
        if (lane < QCH) cellv = qinfo[chunk * QCH + lane] >> 16;
        const int rr = cellv >> 4, cc = cellv & 15;
        const int rf  = __shfl(rr, 0), rl  = __shfl(rr, QCH - 1);
        const int cfi = __shfl(cc, 0), cla = __shfl(cc, QCH - 1);
        const int r0 = max(rf - 1, 0), r1 = min(rl + 1, NGY - 1);
        int c0, c1;
        if (rf == rl) { c0 = max(cfi - 1, 0); c1 = min(cla + 1, NGX - 1); }
        else          { c0 = 0; c1 = NGX - 1; }   // row-spanning: full width
        const int nr = r1 - r0 + 1;               // <= 12
        const int* cs = cstart + b * NCELL1;
        int base = 0, len = 0;
        if (lane < nr) {
            base = cs[(r0 + lane) * CSTRIDE + c0];
            len  = cs[(r0 + lane) * CSTRIDE + c1 + 1] - base;
        }
        int cum = len;
#pragma unroll
        for (int d = 1; d < 16; d <<= 1) {
            const int tv = __shfl(cum, max(lane - d, 0));
            if (lane >= d) cum += tv;
        }
        if (lane < nr) { dbase[lane] = base; dcum[lane + 1] = cum; }
        if (lane == 0) dcum[0] = 0;
        if (lane == nr - 1) sMsh = cum;
    }
    __syncthreads();
    const int M  = sMsh;                   // window size (ctx records)
    const int nt = (M + TS - 1) / TS;      // tiles (<= ~13)

    const float qx = qxy[2 * p], qy = qxy[2 * p + 1];

    // staging role: rec = tid>>1; even thread -> f4 0,1; odd thread -> f4 2
    const int  srec = tid >> 1;            // 0..255
    const bool odd  = tid & 1;

    // ---- prologue: stage tile 0 into buffer 0 ----
    if (nt > 0 && srec < M) {
        int sg = 0;
        while (srec >= dcum[sg + 1]) ++sg;
        const int grow = dbase[sg] + (srec - dcum[sg]);
        const float* gp = crec + ((size_t)b * 4096 + grow) * RECF;
        float* dp = smem + (srec >> 4) * GRPF + (srec & 15) * RECF;
        if (!odd) {
            *(float4*)(dp + 0) = *(const float4*)(gp + 0);
            *(float4*)(dp + 4) = *(const float4*)(gp + 4);
        } else {
            *(float4*)(dp + 8) = *(const float4*)(gp + 8);
        }
    }
    __syncthreads();

    float a0=0.f,a1=0.f,a2=0.f,a3=0.f,a4=0.f,a5=0.f,a6=0.f,a7=0.f,a8=0.f;

    for (int t = 0; t < nt; ++t) {
        const int cur = t & 1;
        // issue next-tile global loads early (latency hides under compute)
        float4 g0, g1, g2;
        bool stg = false;
        if (t + 1 < nt) {
            const int wo = (t + 1) * TS + srec;
            if (wo < M) {
                int sg = 0;
                while (wo >= dcum[sg + 1]) ++sg;
                const int grow = dbase[sg] + (wo - dcum[sg]);
                const float* gp = crec + ((size_t)b * 4096 + grow) * RECF;
                if (!odd) { g0 = *(const float4*)(gp + 0); g1 = *(const float4*)(gp + 4); }
                else      { g2 = *(const float4*)(gp + 8); }
                stg = true;
            }
        }
        // compute tile t from LDS (2 distinct addrs per wave-instr: free)
        const int TC  = min(TS, M - t * TS);
        const int lim = min(max(TC - s * 16, 0), 16);
        const float* tb = smem + cur * BUFF + s * GRPF;
#pragma unroll 4
        for (int i = 0; i < 16; ++i) {
            if (i < lim) {
                const float4 r0v = *(const float4*)(tb + i * RECF + 0);
                const float4 r1v = *(const float4*)(tb + i * RECF + 4);
                const float4 r2v = *(const float4*)(tb + i * RECF + 8);
                const float dx = r0v.x - qx, dy = r0v.y - qy;
                const float w  = EXP2F(-fmaf(dx, dx, dy * dy));
                a8 += w;
                a0 = fmaf(w, r0v.z, a0); a1 = fmaf(w, r0v.w, a1);
                a2 = fmaf(w, r1v.x, a2); a3 = fmaf(w, r1v.y, a3);
                a4 = fmaf(w, r1v.z, a4); a5 = fmaf(w, r1v.w, a5);
                a6 = fmaf(w, r2v.x, a6); a7 = fmaf(w, r2v.y, a7);
            }
        }
        // write staged regs into the other buffer (disjoint from readers)
        if (stg) {
            float* dp = smem + (cur ^ 1) * BUFF + (srec >> 4) * GRPF + (srec & 15) * RECF;
            if (!odd) { *(float4*)(dp + 0) = g0; *(float4*)(dp + 4) = g1; }
            else      { *(float4*)(dp + 8) = g2; }
        }
        __syncthreads();
    }

    // ---- reduce 16 s-partials per query (reuse smem), normalize, write out ----
    float* sred = smem;
    sred[(q * 9 + 0) * SGN + s] = a0;
    sred[(q * 9 + 1) * SGN + s] = a1;
    sred[(q * 9 + 2) * SGN + s] = a2;
    sred[(q * 9 + 3) * SGN + s] = a3;
    sred[(q * 9 + 4) * SGN + s] = a4;
    sred[(q * 9 + 5) * SGN + s] = a5;
    sred[(q * 9 + 6) * SGN + s] = a6;
    sred[(q * 9 + 7) * SGN + s] = a7;
    sred[(q * 9 + 8) * SGN + s] = a8;
    __syncthreads();

    float sum = 0.f;
    const int qq = tid & 31, jj = tid >> 5;   // tid<288: 32 q x 9 j
    if (tid < 288) {
        const float* rp = sred + (qq * 9 + jj) * SGN;
#pragma unroll
        for (int k = 0; k < SGN; ++k) sum += rp[k];
        if (jj == 8) sden[qq] = sum;
    }
    __syncthreads();
    if (tid < 288) {
        const int pp  = chunk * QCH + qq;
        const int qid = qinfo[pp] & 0xFFFF;
        float* o = out + ((size_t)b * 4096 + qid) * 9;
        o[jj] = (jj == 8) ? sum : sum / (sden[qq] + 1e-8f);
    }
}

// ================= MFMA dense path (kept for one-line revert) =================
typedef short bf16x8 __attribute__((ext_vector_type(8)));
typedef float f32x4  __attribute__((ext_vector_type(4)));
typedef float f32x2  __attribute__((ext_vector_type(2)));

__device__ __forceinline__ short f2bf(float v) {
    return (short)(__builtin_bit_cast(unsigned, v) >> 16);
}
__device__ __forceinline__ unsigned fbits(float v) {
    return __builtin_bit_cast(unsigned, v);
}
__device__ __forceinline__ unsigned bfpair(float w0, float w1) {
#if __has_builtin(__builtin_amdgcn_perm)
    return __builtin_amdgcn_perm(fbits(w1), fbits(w0), 0x07060302u);
#else
    return (fbits(w1) & 0xFFFF0000u) | (fbits(w0) >> 16);
#endif
}

#define GSPLIT 8
#define CCHUNK (NC / GSPLIT)
#define NPAIR (CCHUNK / 2)
#define KSTEPS (CCHUNK / 32)
#define QPB 128
#define QB (NBQ / QPB)
#define JS ((size_t)GSPLIT * NBQ)
#define WS_FLOATS ((size_t)(DY + 1) * GSPLIT * NBQ)

__global__ __launch_bounds__(256, 4) void setconv_accum_mfma(
    const float* __restrict__ xq, const float* __restrict__ xc,
    const float* __restrict__ yc, const float* __restrict__ lls,
    float* __restrict__ ws)
{
    __shared__ float4 sxp[NPAIR];
    __shared__ float2 shp[NPAIR];
    __shared__ unsigned short yfrag[CCHUNK / 8][16][8];

    const int bid  = blockIdx.x;
    const int gs   = bid & (GSPLIT - 1);
    const int qb   = bid >> 3;
    const int b    = qb >> 5;
    const int tid  = threadIdx.x;
    const int lane = tid & 63;
    const int wv   = tid >> 6;
    const int m    = lane & 15;
    const int quad = lane >> 4;

    const float L    = lls[0];
    const float negk = -0.72134752044448f * EXP2F(L * -2.8853900817779268f);

    {
        const float4* xcp = (const float4*)(((const float2*)xc) + (size_t)b * NC + gs * CCHUNK);
        const float4 v = xcp[tid];
        sxp[tid] = make_float4(v.x, v.z, v.y, v.w);
        shp[tid] = make_float2(negk * fmaf(v.x, v.x, v.y * v.y),
                               negk * fmaf(v.z, v.z, v.w * v.w));
    }
    {
        const float4* yp = (const float4*)(yc + ((size_t)b * NC + gs * CCHUNK) * DY);
#pragma unroll
        for (int i = 0; i < 2; ++i) {
            const int c = tid + 256 * i;
            const float4 A  = yp[2 * c + 0];
            const float4 Bv = yp[2 * c + 1];
            const int g = c >> 3, j = c & 7;
            unsigned short* dst = &yfrag[g][0][j];
            dst[0 * 8] = (unsigned short)f2bf(A.x);
            dst[1 * 8] = (unsigned short)f2bf(A.y);
            dst[2 * 8] = (unsigned short)f2bf(A.z);
            dst[3 * 8] = (unsigned short)f2bf(A.w);
            dst[4 * 8] = (unsigned short)f2bf(Bv.x);
            dst[5 * 8] = (unsigned short)f2bf(Bv.y);
            dst[6 * 8] = (unsigned short)f2bf(Bv.z);
            dst[7 * 8] = (unsigned short)f2bf(Bv.w);
        }
        unsigned* yf32 = (unsigned*)yfrag;
#pragma unroll
        for (int i = 0; i < 8; ++i) {
            const int v = tid + 256 * i;
            const int g = v >> 5, r = v & 31;
            yf32[g * 64 + 32 + r] = (r < 4) ? 0x3F803F80u : 0u;
        }
    }

    f32x2 A0[2], A1[2], A2[2];
#pragma unroll
    for (int t = 0; t < 2; ++t) {
        const int q = qb * QPB + (wv * 2 + t) * 16 + m;
        const float2 qv = ((const float2*)xq)[q];
        const float c0 = negk * fmaf(qv.x, qv.x, qv.y * qv.y);
        const float c1 = -2.f * negk * qv.x;
        const float c2 = -2.f * negk * qv.y;
        A0[t] = (f32x2){c0, c0};
        A1[t] = (f32x2){c1, c1};
        A2[t] = (f32x2){c2, c2};
    }

    f32x4 acc0 = {0.f, 0.f, 0.f, 0.f};
    f32x4 acc1 = {0.f, 0.f, 0.f, 0.f};

    __syncthreads();

#pragma unroll 2
    for (int s = 0; s < KSTEPS; ++s) {
        const bf16x8 bfrag = *(const bf16x8*)&yfrag[s * 4 + quad][m][0];
        unsigned au0[4], au1[4];
#pragma unroll
        for (int jp = 0; jp < 4; ++jp) {
            const int P = s * 16 + quad * 4 + jp;
            const float4 xp = sxp[P];
            const float2 hp = shp[P];
            const f32x2 cx2 = {xp.x, xp.y};
            const f32x2 cy2 = {xp.z, xp.w};
            const f32x2 hc2 = {hp.x, hp.y};
            f32x2 t0 = __builtin_elementwise_fma(cx2, A1[0], hc2 + A0[0]);
            t0 = __builtin_elementwise_fma(cy2, A2[0], t0);
            f32x2 t1 = __builtin_elementwise_fma(cx2, A1[1], hc2 + A0[1]);
            t1 = __builtin_elementwise_fma(cy2, A2[1], t1);
            au0[jp] = bfpair(EXP2F(t0.x), EXP2F(t0.y));
            au1[jp] = bfpair(EXP2F(t1.x), EXP2F(t1.y));
        }
        const bf16x8 af0 = __builtin_bit_cast(bf16x8, *(uint4*)au0);
        const bf16x8 af1 = __builtin_bit_cast(bf16x8, *(uint4*)au1);
        acc0 = __builtin_amdgcn_mfma_f32_16x16x32_bf16(af0, bfrag, acc0, 0, 0, 0);
        acc1 = __builtin_amdgcn_mfma_f32_16x16x32_bf16(af1, bfrag, acc1, 0, 0, 0);
    }

    if (m <= 8) {
        const size_t base = (size_t)m * JS + (size_t)gs * NBQ + (size_t)qb * QPB;
#pragma unroll
        for (int r = 0; r < 4; ++r) {
            ws[base + (wv * 2 + 0) * 16 + quad * 4 + r] = acc0[r];
            ws[base + (wv * 2 + 1) * 16 + quad * 4 + r] = acc1[r];
        }
    }
}

__global__ __launch_bounds__(256) void setconv_reduce(
    const float* __restrict__ ws, float* __restrict__ out)
{
    __shared__ float partl[4][64][DY + 1];
    const int tid  = threadIdx.x;
    const int qi   = tid & 63;
    const int sgp  = tid >> 6;
    const int base = blockIdx.x * 64;
    const int bq   = base + qi;

#pragma unroll
    for (int j = 0; j < DY + 1; ++j) {
        float sv = 0.f;
#pragma unroll
        for (int k = 0; k < GSPLIT / 4; ++k) {
            const int split = sgp * (GSPLIT / 4) + k;
            sv += ws[(size_t)j * JS + (size_t)split * NBQ + bq];
        }
        partl[sgp][qi][j] = sv;
    }
    __syncthreads();

    for (int it = tid; it < 64 * (DY + 1); it += 256) {
        const int q2 = it / (DY + 1);
        const int j  = it - q2 * (DY + 1);
        const float den = partl[0][q2][DY] + partl[1][q2][DY] +
                          partl[2][q2][DY] + partl[3][q2][DY];
        float v;
        if (j == DY) {
            v = den;
        } else {
            const float sv = partl[0][q2][j] + partl[1][q2][j] +
                             partl[2][q2][j] + partl[3][q2][j];
            v = sv / (den + 1e-8f);
        }
        out[(size_t)base * (DY + 1) + it] = v;
    }
}

// ================= fallback path (round-1, known-good): atomics =================
#define FSPLIT 8
#define FCCH (NC / FSPLIT)

__global__ __launch_bounds__(256) void setconv_zero(float4* __restrict__ out) {
    out[blockIdx.x * 256 + threadIdx.x] = make_float4(0.f, 0.f, 0.f, 0.f);
}

__global__ __launch_bounds__(256) void setconv_accum_atomic(
    const float* __restrict__ xq, const float* __restrict__ xc,
    const float* __restrict__ yc, const float* __restrict__ lls,
    float* __restrict__ out)
{
    const int bid   = blockIdx.x;
    const int split = bid & (FSPLIT - 1);
    const int qblk  = (bid / FSPLIT) & (NQ / 256 - 1);
    const int b     = bid / (FSPLIT * (NQ / 256));
    const int q     = qblk * 256 + threadIdx.x;

    const float L    = lls[0];
    const float negk = -0.72134752044448f * EXP2F(L * -2.8853900817779268f);

    const float2 qv = ((const float2*)xq)[b * NQ + q];
    const float qx0 = qv.x, qy0 = qv.y;

    float acc[DY], den = 0.f;
#pragma unroll
    for (int j = 0; j < DY; ++j) acc[j] = 0.f;

    const float2* __restrict__ xcp = ((const float2*)xc) + (size_t)b * NC;
    const float4* __restrict__ ycp = ((const float4*)yc) + (size_t)b * NC * 2;

    const int c0 = split * FCCH;
#pragma unroll 4
    for (int c = c0; c < c0 + FCCH; ++c) {
        const float2 cv = xcp[c];
        const float4 y0 = ycp[2 * c + 0];
        const float4 y1 = ycp[2 * c + 1];
        const float dx = qx0 - cv.x;
        const float dy = qy0 - cv.y;
        const float d2 = fmaf(dy, dy, dx * dx);
        const float w  = EXP2F(d2 * negk);
        den += w;
        acc[0] = fmaf(w, y0.x, acc[0]);
        acc[1] = fmaf(w, y0.y, acc[1]);
        acc[2] = fmaf(w, y0.z, acc[2]);
        acc[3] = fmaf(w, y0.w, acc[3]);
        acc[4] = fmaf(w, y1.x, acc[4]);
        acc[5] = fmaf(w, y1.y, acc[5]);
        acc[6] = fmaf(w, y1.z, acc[6]);
        acc[7] = fmaf(w, y1.w, acc[7]);
    }

    float* o = out + (size_t)(b * NQ + q) * (DY + 1);
#pragma unroll
    for (int j = 0; j < DY; ++j) atomicAdd(o + j, acc[j]);
    atomicAdd(o + DY, den);
}

__global__ __launch_bounds__(256) void setconv_norm(float* __restrict__ out) {
    const int q = blockIdx.x * 256 + threadIdx.x;
    float* o = out + (size_t)q * (DY + 1);
    const float inv = 1.0f / (o[DY] + 1e-8f);
#pragma unroll
    for (int j = 0; j < DY; ++j) o[j] *= inv;
}

extern "C" void kernel_launch(void* const* d_in, const int* in_sizes, int n_in,
                              void* d_out, int out_size, void* d_ws, size_t ws_size,
                              hipStream_t stream) {
    const float* xq  = (const float*)d_in[0];  // (4,4096,2)
    const float* xc  = (const float*)d_in[1];  // (4,4096,2)
    const float* yc  = (const float*)d_in[2];  // (4,4096,8)
    const float* lls = (const float*)d_in[3];  // scalar
    float* out = (float*)d_out;                // (4,4096,9)

    if (ws_size >= (size_t)WS_NEED_FLOATS * sizeof(float)) {
        float* wsf = (float*)d_ws;
        int*   wsi = (int*)d_ws;
        sc_hist<<<64, 256, 0, stream>>>(xq, xc, wsf);
        sc_scan<<<1, 256, 0, stream>>>(wsf);
        sc_scatter<<<64, 256, 0, stream>>>(xq, xc, yc, lls, wsf);
        sc_chunk<<<NCHK, 512, 0, stream>>>(
            wsf + OFF_CREC, wsi + OFF_CSTART, wsi + OFF_QINFO,
            wsf + OFF_QXY, out);
    } else if (ws_size >= WS_FLOATS * sizeof(float)) {
        float* ws = (float*)d_ws;
        setconv_accum_mfma<<<QB * GSPLIT, 256, 0, stream>>>(xq, xc, yc, lls, ws);
        setconv_reduce<<<NBQ / 64, 256, 0, stream>>>(ws, out);
    } else {
        setconv_zero<<<(NBQ * (DY + 1)) / 1024, 256, 0, stream>>>((float4*)out);
        setconv_accum_atomic<<<BB * (NQ / 256) * FSPLIT, 256, 0, stream>>>(xq, xc, yc, lls, out);
        setconv_norm<<<NBQ / 256, 256, 0, stream>>>(out);
    }
}

// Round 4
// 73.846 us; speedup vs baseline: 1.8758x; 1.6046x over previous
//
#include <hip/hip_runtime.h>

// SetConv RBF: B=4, NQ=4096, NC=4096, DC=2, DY=8, fp32.
// out[b,q,0:8] = sum_c w(q,c)*y[c] / (den+1e-8); out[b,q,8] = den = sum_c w(q,c)
//
// MEASURED LAWS (prior session R1-R10, this session R11-R13):
//  - dur_us includes ~41us harness d_ws poison fill (256MiB, ws-usage-INDEPENDENT)
//    + ~10us fixed overhead. Floor ~51us.
//  - Dense MFMA path: accum ~20us + reduce ~2.5us => 73.6 total (67M pairs).
//  - R11-R13 binning FALSIFIED: 12x12-cell window cuts pairs 67M->21M (absmax
//    0.0019 proves numerics) but the pipeline tax (sort+scan+scatter+gaps
//    12-20us) + latency/imbalance in the sparse accumulator always >= saving.
//    Best measured 118us. Global-load-per-trip loops are latency-bound at any
//    occupancy (R12: VALU 16%, occ 48%).
//  - R10 LAW (reinterpreted): -30% VALU instrs = null => dense accum is NOT
//    VALU-bound. Arithmetic: 9 DS/k-step/wave x ~8cyc x 16 redundant waves/CU
//    ~= 21us of per-CU LDS-instruction-pipe time == measured 20us. The accum
//    is LDS-INSTRUCTION-THROUGHPUT bound; sxp/shp are read 4x redundantly.
// R14: k-major wave split. Wave wv owns k-steps {4wv..4wv+3} x ALL 8 q-tiles
// (was: 2 q-tiles x all 16 k-steps). ctx stream read ONCE per block per k-step
// -> LDS instrs /4 (~21->5us). VALU/exp/MFMA conserved. Epilogue: cross-wave
// acc reduce via 8KB LDS (yfrag reuse), conflict-free [u][w][lane][r] layout.
// Predicted: accum 20->11-14us, total 73.6 -> 64-68us, absmax ~0.25.

#define BB 4
#define NQ 4096
#define NC 4096
#define DY 8
#define NBQ (BB * NQ)           // 16384 queries total

#if __has_builtin(__builtin_amdgcn_exp2f)
#define EXP2F(x) __builtin_amdgcn_exp2f(x)
#else
#define EXP2F(x) exp2f(x)
#endif

typedef short bf16x8 __attribute__((ext_vector_type(8)));
typedef float f32x4  __attribute__((ext_vector_type(4)));
typedef float f32x2  __attribute__((ext_vector_type(2)));

__device__ __forceinline__ short f2bf(float v) {
    return (short)(__builtin_bit_cast(unsigned, v) >> 16);   // truncate
}
__device__ __forceinline__ unsigned fbits(float v) {
    return __builtin_bit_cast(unsigned, v);
}
// pack hi16(w0) -> low half, hi16(w1) -> high half (bf16 pair dword)
__device__ __forceinline__ unsigned bfpair(float w0, float w1) {
#if __has_builtin(__builtin_amdgcn_perm)
    return __builtin_amdgcn_perm(fbits(w1), fbits(w0), 0x07060302u);
#else
    return (fbits(w1) & 0xFFFF0000u) | (fbits(w0) >> 16);
#endif
}

// ---------------- fast path (MFMA, k-major waves) ----------------
#define GSPLIT 8                     // global context split
#define CCHUNK (NC / GSPLIT)         // 512 contexts per block
#define NPAIR (CCHUNK / 2)           // 256 context pairs
#define KSTEPS (CCHUNK / 32)         // 16 mfma k-steps
#define QPB 128                      // queries per block: 8 tiles x 16
#define NT 8                         // q-tiles per block
#define KPW (KSTEPS / 4)             // 4 k-steps per wave
#define QB (NBQ / QPB)               // 128 query-blocks
#define JS ((size_t)GSPLIT * NBQ)                     // 131072
#define WS_FLOATS ((size_t)(DY + 1) * GSPLIT * NBQ)   // 1.18M floats = 4.7 MB

// grid = QB*GSPLIT = 1024 blocks of 256 = 4 blocks/CU resident.
__global__ __launch_bounds__(256, 4) void setconv_accum_mfma(
    const float* __restrict__ xq, const float* __restrict__ xc,
    const float* __restrict__ yc, const float* __restrict__ lls,
    float* __restrict__ ws)
{
    __shared__ float4 sxp[NPAIR];                        // (cx0,cx1,cy0,cy1) 4 KB
    __shared__ float2 shp[NPAIR];                        // (hc0,hc1)         2 KB
    __shared__ __attribute__((aligned(16)))
        unsigned short yfrag[CCHUNK / 8][16][8];         // B-frag layout    16 KB

    const int bid  = blockIdx.x;              // 0..1023
    const int gs   = bid & (GSPLIT - 1);
    const int qb   = bid >> 3;                // 0..127
    const int b    = qb >> 5;                 // 32 q-blocks per batch
    const int tid  = threadIdx.x;
    const int lane = tid & 63;
    const int wv   = tid >> 6;
    const int m    = lane & 15;               // A row / D col index
    const int quad = lane >> 4;

    const float L    = lls[0];
    const float negk = -0.72134752044448f * EXP2F(L * -2.8853900817779268f);

    // ---- stage ctx pairs: tid == pair index (unchanged, proven) ----
    {
        const float4* xcp = (const float4*)(((const float2*)xc) + (size_t)b * NC + gs * CCHUNK);
        const float4 v = xcp[tid];            // (cx0,cy0,cx1,cy1)
        sxp[tid] = make_float4(v.x, v.z, v.y, v.w);
        shp[tid] = make_float2(negk * fmaf(v.x, v.x, v.y * v.y),
                               negk * fmaf(v.z, v.z, v.w * v.w));
    }
    // ---- stage Ytilde in B-fragment layout: yfrag[g][n][j] = Y[8g+j][n] ----
    {
        const float4* yp = (const float4*)(yc + ((size_t)b * NC + gs * CCHUNK) * DY);
#pragma unroll
        for (int i = 0; i < 2; ++i) {
            const int c = tid + 256 * i;
            const float4 A  = yp[2 * c + 0];
            const float4 Bv = yp[2 * c + 1];
            const int g = c >> 3, j = c & 7;
            unsigned short* dst = &yfrag[g][0][j];
            dst[0 * 8] = (unsigned short)f2bf(A.x);
            dst[1 * 8] = (unsigned short)f2bf(A.y);
            dst[2 * 8] = (unsigned short)f2bf(A.z);
            dst[3 * 8] = (unsigned short)f2bf(A.w);
            dst[4 * 8] = (unsigned short)f2bf(Bv.x);
            dst[5 * 8] = (unsigned short)f2bf(Bv.y);
            dst[6 * 8] = (unsigned short)f2bf(Bv.z);
            dst[7 * 8] = (unsigned short)f2bf(Bv.w);
        }
        // cols 8..15: col 8 = 1.0 (density), 9..15 = 0
        unsigned* yf32 = (unsigned*)yfrag;    // u32 idx = g*64 + n*4 + (j>>1)
#pragma unroll
        for (int i = 0; i < 8; ++i) {         // (CCHUNK/8)*32/256 = 8
            const int v = tid + 256 * i;
            const int g = v >> 5, r = v & 31; // r = (n-8)*4 + jpair
            yf32[g * 64 + 32 + r] = (r < 4) ? 0x3F803F80u : 0u;
        }
    }

    // ---- per-query coefficients for ALL 8 tiles (lane m = query row) ----
    float A0s[NT], A1s[NT], A2s[NT];
#pragma unroll
    for (int t = 0; t < NT; ++t) {
        const int q = qb * QPB + t * 16 + m;
        const float2 qv = ((const float2*)xq)[q];
        A0s[t] = negk * fmaf(qv.x, qv.x, qv.y * qv.y);
        A1s[t] = -2.f * negk * qv.x;
        A2s[t] = -2.f * negk * qv.y;
    }

    f32x4 acc[NT];
#pragma unroll
    for (int t = 0; t < NT; ++t) acc[t] = (f32x4){0.f, 0.f, 0.f, 0.f};

    __syncthreads();

    // ---- hot loop: wave wv owns k-steps 4wv..4wv+3, ALL 8 q-tiles.
    //      Per k-step: 9 DS reads (once per block-worth of 8 tiles), then
    //      8 x (4 jp x {2 pk-fma, pk-add} + 8 exp + 4 pack) + 8 MFMA. ----
    for (int ks = 0; ks < KPW; ++ks) {
        const int s = wv * KPW + ks;
        const bf16x8 bfrag = *(const bf16x8*)&yfrag[s * 4 + quad][m][0];
        float4 xp[4]; float2 hp[4];
#pragma unroll
        for (int jp = 0; jp < 4; ++jp) {
            const int P = s * 16 + quad * 4 + jp;
            xp[jp] = sxp[P];
            hp[jp] = shp[P];
        }
#pragma unroll
        for (int t = 0; t < NT; ++t) {
            const f32x2 a0 = {A0s[t], A0s[t]};
            const f32x2 a1 = {A1s[t], A1s[t]};
            const f32x2 a2 = {A2s[t], A2s[t]};
            unsigned au[4];
#pragma unroll
            for (int jp = 0; jp < 4; ++jp) {
                const f32x2 cx2 = {xp[jp].x, xp[jp].y};
                const f32x2 cy2 = {xp[jp].z, xp[jp].w};
                const f32x2 hc2 = {hp[jp].x, hp[jp].y};
                f32x2 tt = __builtin_elementwise_fma(cx2, a1, hc2 + a0);
                tt = __builtin_elementwise_fma(cy2, a2, tt);
                au[jp] = bfpair(EXP2F(tt.x), EXP2F(tt.y));
            }
            const bf16x8 af = __builtin_bit_cast(bf16x8, *(uint4*)au);
            acc[t] = __builtin_amdgcn_mfma_f32_16x16x32_bf16(af, bfrag, acc[t], 0, 0, 0);
        }
    }

    // ---- cross-wave reduce of partial accumulators (k-split), write ws ----
    // rb layout [u][w][lane][r]: lane stride 16B -> conflict-free b128.
    __syncthreads();                          // all yfrag/sxp reads done
    float4* rb = (float4*)&yfrag[0][0][0];    // 2*4*64 float4 = 8 KB reuse
    for (int h = 0; h < 4; ++h) {             // 2 tiles per round
#pragma unroll
        for (int u = 0; u < 2; ++u) {
            const int t = h * 2 + u;
            rb[(u * 4 + wv) * 64 + lane] =
                make_float4(acc[t][0], acc[t][1], acc[t][2], acc[t][3]);
        }
        __syncthreads();
        if (wv == h && m <= 8) {
#pragma unroll
            for (int u = 0; u < 2; ++u) {
                const int t = h * 2 + u;
                float4 v = rb[(u * 4 + 0) * 64 + lane];
#pragma unroll
                for (int w = 1; w < 4; ++w) {
                    const float4 z = rb[(u * 4 + w) * 64 + lane];
                    v.x += z.x; v.y += z.y; v.z += z.z; v.w += z.w;
                }
                *(float4*)&ws[(size_t)m * JS + (size_t)gs * NBQ +
                              (size_t)qb * QPB + t * 16 + quad * 4] = v;
            }
        }
        __syncthreads();
    }
}

// Reduce over GSPLIT=8 + normalize (R4/R8/R9-proven). Block: 64 queries,
// 4 groups of 2 splits. Grid = NBQ/64 = 256 blocks.
__global__ __launch_bounds__(256) void setconv_reduce(
    const float* __restrict__ ws, float* __restrict__ out)
{
    __shared__ float part[4][64][DY + 1];
    const int tid  = threadIdx.x;
    const int qi   = tid & 63;
    const int sg   = tid >> 6;
    const int base = blockIdx.x * 64;
    const int bq   = base + qi;

#pragma unroll
    for (int j = 0; j < DY + 1; ++j) {
        float s = 0.f;
#pragma unroll
        for (int k = 0; k < GSPLIT / 4; ++k) {
            const int split = sg * (GSPLIT / 4) + k;
            s += ws[(size_t)j * JS + (size_t)split * NBQ + bq];  // coalesced
        }
        part[sg][qi][j] = s;
    }
    __syncthreads();

    for (int it = tid; it < 64 * (DY + 1); it += 256) {
        const int q2 = it / (DY + 1);
        const int j  = it - q2 * (DY + 1);
        const float den = part[0][q2][DY] + part[1][q2][DY] +
                          part[2][q2][DY] + part[3][q2][DY];
        float v;
        if (j == DY) {
            v = den;
        } else {
            const float s = part[0][q2][j] + part[1][q2][j] +
                            part[2][q2][j] + part[3][q2][j];
            v = s / (den + 1e-8f);
        }
        out[(size_t)base * (DY + 1) + it] = v;    // coalesced
    }
}

// ---------------- fallback path (round-1, known-good): atomics ----------------
#define FSPLIT 8
#define FCCH (NC / FSPLIT)

__global__ __launch_bounds__(256) void setconv_zero(float4* __restrict__ out) {
    out[blockIdx.x * 256 + threadIdx.x] = make_float4(0.f, 0.f, 0.f, 0.f);
}

__global__ __launch_bounds__(256) void setconv_accum_atomic(
    const float* __restrict__ xq, const float* __restrict__ xc,
    const float* __restrict__ yc, const float* __restrict__ lls,
    float* __restrict__ out)
{
    const int bid   = blockIdx.x;
    const int split = bid & (FSPLIT - 1);
    const int qblk  = (bid / FSPLIT) & (NQ / 256 - 1);
    const int b     = bid / (FSPLIT * (NQ / 256));
    const int q     = qblk * 256 + threadIdx.x;

    const float L    = lls[0];
    const float negk = -0.72134752044448f * EXP2F(L * -2.8853900817779268f);

    const float2 qv = ((const float2*)xq)[b * NQ + q];
    const float qx0 = qv.x, qy0 = qv.y;

    float acc[DY], den = 0.f;
#pragma unroll
    for (int j = 0; j < DY; ++j) acc[j] = 0.f;

    const float2* __restrict__ xcp = ((const float2*)xc) + (size_t)b * NC;
    const float4* __restrict__ ycp = ((const float4*)yc) + (size_t)b * NC * 2;

    const int c0 = split * FCCH;
#pragma unroll 4
    for (int c = c0; c < c0 + FCCH; ++c) {
        const float2 cv = xcp[c];
        const float4 y0 = ycp[2 * c + 0];
        const float4 y1 = ycp[2 * c + 1];
        const float dx = qx0 - cv.x;
        const float dy = qy0 - cv.y;
        const float d2 = fmaf(dy, dy, dx * dx);
        const float w  = EXP2F(d2 * negk);
        den += w;
        acc[0] = fmaf(w, y0.x, acc[0]);
        acc[1] = fmaf(w, y0.y, acc[1]);
        acc[2] = fmaf(w, y0.z, acc[2]);
        acc[3] = fmaf(w, y0.w, acc[3]);
        acc[4] = fmaf(w, y1.x, acc[4]);
        acc[5] = fmaf(w, y1.y, acc[5]);
        acc[6] = fmaf(w, y1.z, acc[6]);
        acc[7] = fmaf(w, y1.w, acc[7]);
    }

    float* o = out + (size_t)(b * NQ + q) * (DY + 1);
#pragma unroll
    for (int j = 0; j < DY; ++j) atomicAdd(o + j, acc[j]);
    atomicAdd(o + DY, den);
}

__global__ __launch_bounds__(256) void setconv_norm(float* __restrict__ out) {
    const int q = blockIdx.x * 256 + threadIdx.x;
    float* o = out + (size_t)q * (DY + 1);
    const float inv = 1.0f / (o[DY] + 1e-8f);
#pragma unroll
    for (int j = 0; j < DY; ++j) o[j] *= inv;
}

extern "C" void kernel_launch(void* const* d_in, const int* in_sizes, int n_in,
                              void* d_out, int out_size, void* d_ws, size_t ws_size,
                              hipStream_t stream) {
    const float* xq  = (const float*)d_in[0];  // (4,4096,2)
    const float* xc  = (const float*)d_in[1];  // (4,4096,2)
    const float* yc  = (const float*)d_in[2];  // (4,4096,8)
    const float* lls = (const float*)d_in[3];  // scalar
    float* out = (float*)d_out;                // (4,4096,9)

    if (ws_size >= WS_FLOATS * sizeof(float)) {
        float* ws = (float*)d_ws;
        setconv_accum_mfma<<<QB * GSPLIT, 256, 0, stream>>>(xq, xc, yc, lls, ws);
        setconv_reduce<<<NBQ / 64, 256, 0, stream>>>(ws, out);
    } else {
        setconv_zero<<<(NBQ * (DY + 1)) / 1024, 256, 0, stream>>>((float4*)out);
        setconv_accum_atomic<<<BB * (NQ / 256) * FSPLIT, 256, 0, stream>>>(xq, xc, yc, lls, out);
        setconv_norm<<<NBQ / 256, 256, 0, stream>>>(out);
    }
}

// Round 5
// 73.571 us; speedup vs baseline: 1.8828x; 1.0037x over previous
//
#include <hip/hip_runtime.h>

// SetConv RBF: B=4, NQ=4096, NC=4096, DC=2, DY=8, fp32.
// out[b,q,0:8] = sum_c w(q,c)*y[c] / (den+1e-8); out[b,q,8] = den = sum_c w(q,c)
//
// MEASURED LAWS (prior session R1-R10, this session R11-R14):
//  - dur_us = ~41us harness d_ws poison fill + ~10-12us fixed + kernel time.
//    Floor ~51-53us. Top-5 rocprof rows are always the 40us fills.
//  - Dense MFMA path: accum ~20us + reduce ~2.5us => 73.6-73.8 total (67M pairs).
//  - R11-R13 binning FALSIFIED (best 118us): pipeline tax + latency-bound sparse
//    loops >= pair saving. Global-load-per-trip loops latency-bound at any occ.
//  - ACCUM INVARIANCE (R9/R10/R14): accum ~20us is invariant to VALU count
//    (-30% null), DS instr count (-75% null), DS bytes, wave partition.
//    Issue-cost model says hot loop ~5-9us => accum is STALL-bound: per-unit
//    dep chain (pk-fma x3 -> exp x2 -> perm -> MFMA, ~40-60cyc) with only
//    4 waves/SIMD resident (constant across ALL prior variants).
//    Untested alternative: v_exp_f32 slower than modeled (R16: poly-exp A/B).
// R15: occupancy isolated. Same hot-loop instruction sequence as R14; QPB 64
// (NT=4), 2048 blocks, launch_bounds(256,6) (VGPR cap 84, est ~75-85 live)
// -> 6 waves/SIMD vs 4. Work conserved (131072 units).
// Predicted: stall-bound => accum 20->13-15, total 66-69. Null => exp-pipe
// suspect. >77 => VGPR spill, revert cap.

#define BB 4
#define NQ 4096
#define NC 4096
#define DY 8
#define NBQ (BB * NQ)           // 16384 queries total

#if __has_builtin(__builtin_amdgcn_exp2f)
#define EXP2F(x) __builtin_amdgcn_exp2f(x)
#else
#define EXP2F(x) exp2f(x)
#endif

typedef short bf16x8 __attribute__((ext_vector_type(8)));
typedef float f32x4  __attribute__((ext_vector_type(4)));
typedef float f32x2  __attribute__((ext_vector_type(2)));

__device__ __forceinline__ short f2bf(float v) {
    return (short)(__builtin_bit_cast(unsigned, v) >> 16);   // truncate
}
__device__ __forceinline__ unsigned fbits(float v) {
    return __builtin_bit_cast(unsigned, v);
}
// pack hi16(w0) -> low half, hi16(w1) -> high half (bf16 pair dword)
__device__ __forceinline__ unsigned bfpair(float w0, float w1) {
#if __has_builtin(__builtin_amdgcn_perm)
    return __builtin_amdgcn_perm(fbits(w1), fbits(w0), 0x07060302u);
#else
    return (fbits(w1) & 0xFFFF0000u) | (fbits(w0) >> 16);
#endif
}

// ---------------- fast path (MFMA, k-major waves, high occupancy) ----------------
#define GSPLIT 8                     // global context split
#define CCHUNK (NC / GSPLIT)         // 512 contexts per block
#define NPAIR (CCHUNK / 2)           // 256 context pairs
#define KSTEPS (CCHUNK / 32)         // 16 mfma k-steps
#define QPB 64                       // queries per block: 4 tiles x 16
#define NT 4                         // q-tiles per block
#define KPW (KSTEPS / 4)             // 4 k-steps per wave
#define QB (NBQ / QPB)               // 256 query-blocks
#define JS ((size_t)GSPLIT * NBQ)                     // 131072
#define WS_FLOATS ((size_t)(DY + 1) * GSPLIT * NBQ)   // 1.18M floats = 4.7 MB

// grid = QB*GSPLIT = 2048 blocks of 256; LDS 22KB (<=7 blk/CU), VGPR cap 84
// via launch_bounds(256,6) -> target 6 blocks/CU resident (6 waves/SIMD).
__global__ __launch_bounds__(256, 6) void setconv_accum_mfma(
    const float* __restrict__ xq, const float* __restrict__ xc,
    const float* __restrict__ yc, const float* __restrict__ lls,
    float* __restrict__ ws)
{
    __shared__ float4 sxp[NPAIR];                        // (cx0,cx1,cy0,cy1) 4 KB
    __shared__ float2 shp[NPAIR];                        // (hc0,hc1)         2 KB
    __shared__ __attribute__((aligned(16)))
        unsigned short yfrag[CCHUNK / 8][16][8];         // B-frag layout    16 KB

    const int bid  = blockIdx.x;              // 0..2047
    const int gs   = bid & (GSPLIT - 1);
    const int qb   = bid >> 3;                // 0..255
    const int b    = qb >> 6;                 // 64 q-blocks per batch
    const int tid  = threadIdx.x;
    const int lane = tid & 63;
    const int wv   = tid >> 6;
    const int m    = lane & 15;               // A row / D col index
    const int quad = lane >> 4;

    const float L    = lls[0];
    const float negk = -0.72134752044448f * EXP2F(L * -2.8853900817779268f);

    // ---- stage ctx pairs: tid == pair index (proven) ----
    {
        const float4* xcp = (const float4*)(((const float2*)xc) + (size_t)b * NC + gs * CCHUNK);
        const float4 v = xcp[tid];            // (cx0,cy0,cx1,cy1)
        sxp[tid] = make_float4(v.x, v.z, v.y, v.w);
        shp[tid] = make_float2(negk * fmaf(v.x, v.x, v.y * v.y),
                               negk * fmaf(v.z, v.z, v.w * v.w));
    }
    // ---- stage Ytilde in B-fragment layout: yfrag[g][n][j] = Y[8g+j][n] ----
    {
        const float4* yp = (const float4*)(yc + ((size_t)b * NC + gs * CCHUNK) * DY);
#pragma unroll
        for (int i = 0; i < 2; ++i) {
            const int c = tid + 256 * i;
            const float4 A  = yp[2 * c + 0];
            const float4 Bv = yp[2 * c + 1];
            const int g = c >> 3, j = c & 7;
            unsigned short* dst = &yfrag[g][0][j];
            dst[0 * 8] = (unsigned short)f2bf(A.x);
            dst[1 * 8] = (unsigned short)f2bf(A.y);
            dst[2 * 8] = (unsigned short)f2bf(A.z);
            dst[3 * 8] = (unsigned short)f2bf(A.w);
            dst[4 * 8] = (unsigned short)f2bf(Bv.x);
            dst[5 * 8] = (unsigned short)f2bf(Bv.y);
            dst[6 * 8] = (unsigned short)f2bf(Bv.z);
            dst[7 * 8] = (unsigned short)f2bf(Bv.w);
        }
        // cols 8..15: col 8 = 1.0 (density), 9..15 = 0
        unsigned* yf32 = (unsigned*)yfrag;    // u32 idx = g*64 + n*4 + (j>>1)
#pragma unroll
        for (int i = 0; i < 8; ++i) {         // (CCHUNK/8)*32/256 = 8
            const int v = tid + 256 * i;
            const int g = v >> 5, r = v & 31; // r = (n-8)*4 + jpair
            yf32[g * 64 + 32 + r] = (r < 4) ? 0x3F803F80u : 0u;
        }
    }

    // ---- per-query coefficients for the 4 tiles (lane m = query row) ----
    float A0s[NT], A1s[NT], A2s[NT];
#pragma unroll
    for (int t = 0; t < NT; ++t) {
        const int q = qb * QPB + t * 16 + m;
        const float2 qv = ((const float2*)xq)[q];
        A0s[t] = negk * fmaf(qv.x, qv.x, qv.y * qv.y);
        A1s[t] = -2.f * negk * qv.x;
        A2s[t] = -2.f * negk * qv.y;
    }

    f32x4 acc[NT];
#pragma unroll
    for (int t = 0; t < NT; ++t) acc[t] = (f32x4){0.f, 0.f, 0.f, 0.f};

    __syncthreads();

    // ---- hot loop: wave wv owns k-steps 4wv..4wv+3, all 4 q-tiles.
    //      Identical per-pair instruction sequence to R14 (occupancy isolated).
    for (int ks = 0; ks < KPW; ++ks) {
        const int s = wv * KPW + ks;
        const bf16x8 bfrag = *(const bf16x8*)&yfrag[s * 4 + quad][m][0];
        float4 xp[4]; float2 hp[4];
#pragma unroll
        for (int jp = 0; jp < 4; ++jp) {
            const int P = s * 16 + quad * 4 + jp;
            xp[jp] = sxp[P];
            hp[jp] = shp[P];
        }
#pragma unroll
        for (int t = 0; t < NT; ++t) {
            const f32x2 a0 = {A0s[t], A0s[t]};
            const f32x2 a1 = {A1s[t], A1s[t]};
            const f32x2 a2 = {A2s[t], A2s[t]};
            unsigned au[4];
#pragma unroll
            for (int jp = 0; jp < 4; ++jp) {
                const f32x2 cx2 = {xp[jp].x, xp[jp].y};
                const f32x2 cy2 = {xp[jp].z, xp[jp].w};
                const f32x2 hc2 = {hp[jp].x, hp[jp].y};
                f32x2 tt = __builtin_elementwise_fma(cx2, a1, hc2 + a0);
                tt = __builtin_elementwise_fma(cy2, a2, tt);
                au[jp] = bfpair(EXP2F(tt.x), EXP2F(tt.y));
            }
            const bf16x8 af = __builtin_bit_cast(bf16x8, *(uint4*)au);
            acc[t] = __builtin_amdgcn_mfma_f32_16x16x32_bf16(af, bfrag, acc[t], 0, 0, 0);
        }
    }

    // ---- cross-wave reduce of k-split partials, write ws (1 tile/round) ----
    // rb layout [w][lane]: lane stride 16B -> conflict-free b128. 4KB in yfrag.
    __syncthreads();                          // all yfrag/sxp reads done
    float4* rb = (float4*)&yfrag[0][0][0];
    for (int h = 0; h < NT; ++h) {
        rb[wv * 64 + lane] = make_float4(acc[h][0], acc[h][1], acc[h][2], acc[h][3]);
        __syncthreads();
        if (wv == h && m <= 8) {
            float4 v = rb[0 * 64 + lane];
#pragma unroll
            for (int w = 1; w < 4; ++w) {
                const float4 z = rb[w * 64 + lane];
                v.x += z.x; v.y += z.y; v.z += z.z; v.w += z.w;
            }
            *(float4*)&ws[(size_t)m * JS + (size_t)gs * NBQ +
                          (size_t)qb * QPB + h * 16 + quad * 4] = v;
        }
        __syncthreads();
    }
}

// Reduce over GSPLIT=8 + normalize (proven). Block: 64 queries,
// 4 groups of 2 splits. Grid = NBQ/64 = 256 blocks.
__global__ __launch_bounds__(256) void setconv_reduce(
    const float* __restrict__ ws, float* __restrict__ out)
{
    __shared__ float part[4][64][DY + 1];
    const int tid  = threadIdx.x;
    const int qi   = tid & 63;
    const int sg   = tid >> 6;
    const int base = blockIdx.x * 64;
    const int bq   = base + qi;

#pragma unroll
    for (int j = 0; j < DY + 1; ++j) {
        float s = 0.f;
#pragma unroll
        for (int k = 0; k < GSPLIT / 4; ++k) {
            const int split = sg * (GSPLIT / 4) + k;
            s += ws[(size_t)j * JS + (size_t)split * NBQ + bq];  // coalesced
        }
        part[sg][qi][j] = s;
    }
    __syncthreads();

    for (int it = tid; it < 64 * (DY + 1); it += 256) {
        const int q2 = it / (DY + 1);
        const int j  = it - q2 * (DY + 1);
        const float den = part[0][q2][DY] + part[1][q2][DY] +
                          part[2][q2][DY] + part[3][q2][DY];
        float v;
        if (j == DY) {
            v = den;
        } else {
            const float s = part[0][q2][j] + part[1][q2][j] +
                            part[2][q2][j] + part[3][q2][j];
            v = s / (den + 1e-8f);
        }
        out[(size_t)base * (DY + 1) + it] = v;    // coalesced
    }
}

// ---------------- fallback path (round-1, known-good): atomics ----------------
#define FSPLIT 8
#define FCCH (NC / FSPLIT)

__global__ __launch_bounds__(256) void setconv_zero(float4* __restrict__ out) {
    out[blockIdx.x * 256 + threadIdx.x] = make_float4(0.f, 0.f, 0.f, 0.f);
}

__global__ __launch_bounds__(256) void setconv_accum_atomic(
    const float* __restrict__ xq, const float* __restrict__ xc,
    const float* __restrict__ yc, const float* __restrict__ lls,
    float* __restrict__ out)
{
    const int bid   = blockIdx.x;
    const int split = bid & (FSPLIT - 1);
    const int qblk  = (bid / FSPLIT) & (NQ / 256 - 1);
    const int b     = bid / (FSPLIT * (NQ / 256));
    const int q     = qblk * 256 + threadIdx.x;

    const float L    = lls[0];
    const float negk = -0.72134752044448f * EXP2F(L * -2.8853900817779268f);

    const float2 qv = ((const float2*)xq)[b * NQ + q];
    const float qx0 = qv.x, qy0 = qv.y;

    float acc[DY], den = 0.f;
#pragma unroll
    for (int j = 0; j < DY; ++j) acc[j] = 0.f;

    const float2* __restrict__ xcp = ((const float2*)xc) + (size_t)b * NC;
    const float4* __restrict__ ycp = ((const float4*)yc) + (size_t)b * NC * 2;

    const int c0 = split * FCCH;
#pragma unroll 4
    for (int c = c0; c < c0 + FCCH; ++c) {
        const float2 cv = xcp[c];
        const float4 y0 = ycp[2 * c + 0];
        const float4 y1 = ycp[2 * c + 1];
        const float dx = qx0 - cv.x;
        const float dy = qy0 - cv.y;
        const float d2 = fmaf(dy, dy, dx * dx);
        const float w  = EXP2F(d2 * negk);
        den += w;
        acc[0] = fmaf(w, y0.x, acc[0]);
        acc[1] = fmaf(w, y0.y, acc[1]);
        acc[2] = fmaf(w, y0.z, acc[2]);
        acc[3] = fmaf(w, y0.w, acc[3]);
        acc[4] = fmaf(w, y1.x, acc[4]);
        acc[5] = fmaf(w, y1.y, acc[5]);
        acc[6] = fmaf(w, y1.z, acc[6]);
        acc[7] = fmaf(w, y1.w, acc[7]);
    }

    float* o = out + (size_t)(b * NQ + q) * (DY + 1);
#pragma unroll
    for (int j = 0; j < DY; ++j) atomicAdd(o + j, acc[j]);
    atomicAdd(o + DY, den);
}

__global__ __launch_bounds__(256) void setconv_norm(float* __restrict__ out) {
    const int q = blockIdx.x * 256 + threadIdx.x;
    float* o = out + (size_t)q * (DY + 1);
    const float inv = 1.0f / (o[DY] + 1e-8f);
#pragma unroll
    for (int j = 0; j < DY; ++j) o[j] *= inv;
}

extern "C" void kernel_launch(void* const* d_in, const int* in_sizes, int n_in,
                              void* d_out, int out_size, void* d_ws, size_t ws_size,
                              hipStream_t stream) {
    const float* xq  = (const float*)d_in[0];  // (4,4096,2)
    const float* xc  = (const float*)d_in[1];  // (4,4096,2)
    const float* yc  = (const float*)d_in[2];  // (4,4096,8)
    const float* lls = (const float*)d_in[3];  // scalar
    float* out = (float*)d_out;                // (4,4096,9)

    if (ws_size >= WS_FLOATS * sizeof(float)) {
        float* ws = (float*)d_ws;
        setconv_accum_mfma<<<QB * GSPLIT, 256, 0, stream>>>(xq, xc, yc, lls, ws);
        setconv_reduce<<<NBQ / 64, 256, 0, stream>>>(ws, out);
    } else {
        setconv_zero<<<(NBQ * (DY + 1)) / 1024, 256, 0, stream>>>((float4*)out);
        setconv_accum_atomic<<<BB * (NQ / 256) * FSPLIT, 256, 0, stream>>>(xq, xc, yc, lls, out);
        setconv_norm<<<NBQ / 256, 256, 0, stream>>>(out);
    }
}